// Round 12
// baseline (4297.401 us; speedup 1.0000x reference)
//
#include <hip/hip_runtime.h>
#include <cstdint>

#define T_STEPS 1024
#define I_DIM 128
#define H_DIM 256
// grid: 256 blocks x 64 threads (ONE wave per WG), PLAIN launch. Co-residency by capacity:
// one-wave blocks always fit >=1/CU, 256 blocks <= 256 CUs -> all resident at t=0.
// grp = blk&15 (16 batch rows), cwg = blk>>4 (16 H cols, all 4 gates in-wave).
// Exchange = R4-proven tagged slots: slot(parity,row,cp) = 8B [2xbf16 | u32 step tag], sc0 sc1,
// parity double-buffer, fire-and-forget publish, poll==gather, unbounded poll, clique WAR
// induction -> deadlock-free with no placement assumptions.
// CODEGEN-SAFETY INVARIANT (the R11 hang fix): every asm load block contains its own
// s_waitcnt vmcnt(0), so all asm outputs are VALID at block exit. Compiler spills can then only
// copy valid data -> spills are a perf issue, never a correctness/liveness issue.

typedef __attribute__((ext_vector_type(8))) short bf16x8;
typedef __attribute__((ext_vector_type(4))) float f32x4;
typedef __attribute__((ext_vector_type(2))) unsigned int u32x2;

__device__ __forceinline__ uint32_t f2bf(float f) {
    uint32_t u = __builtin_bit_cast(uint32_t, f);
    return (u + 0x7FFFu + ((u >> 16) & 1u)) >> 16;   // RNE
}
__device__ __forceinline__ uint32_t pk2bf(float lo, float hi) {
    return (f2bf(lo) & 0xFFFFu) | (f2bf(hi) << 16);
}
__device__ __forceinline__ float bcf(uint32_t u) { return __builtin_bit_cast(float, u); }
__device__ __forceinline__ float sigmoid_(float v) { return 1.f / (1.f + __expf(-v)); }
__device__ __forceinline__ float tanh_(float v) { float e = __expf(2.f * v); return 1.f - 2.f / (e + 1.f); }

// OR of all 32 slot tags XOR e (0 iff every tag == e)
#define TAGOR(e) ( (sg0.y^(e))|(sg0.w^(e))|(sg1.y^(e))|(sg1.w^(e)) \
                 | (sg2.y^(e))|(sg2.w^(e))|(sg3.y^(e))|(sg3.w^(e)) \
                 | (sg4.y^(e))|(sg4.w^(e))|(sg5.y^(e))|(sg5.w^(e)) \
                 | (sg6.y^(e))|(sg6.w^(e))|(sg7.y^(e))|(sg7.w^(e)) \
                 | (sg8.y^(e))|(sg8.w^(e))|(sg9.y^(e))|(sg9.w^(e)) \
                 | (sg10.y^(e))|(sg10.w^(e))|(sg11.y^(e))|(sg11.w^(e)) \
                 | (sg12.y^(e))|(sg12.w^(e))|(sg13.y^(e))|(sg13.w^(e)) \
                 | (sg14.y^(e))|(sg14.w^(e))|(sg15.y^(e))|(sg15.w^(e)) )

// recurrent MFMA for K-chunk Q from slot pair (A0,A1); data words .x/.z are 2xbf16 each
#define SMFMA(Q, A0, A1) do {                                                  \
    uint4 af_; af_.x = (A0).x; af_.y = (A0).z; af_.z = (A1).x; af_.w = (A1).z; \
    _Pragma("unroll")                                                          \
    for (int g_ = 0; g_ < 4; ++g_)                                             \
        acc[g_] = __builtin_amdgcn_mfma_f32_16x16x32_bf16(                     \
            __builtin_bit_cast(bf16x8, af_), __builtin_bit_cast(bf16x8, bwh[g_][Q]), \
            acc[g_], 0, 0, 0);                                                 \
} while (0)

// x-part MFMA for K-chunk Q from f32 pair (X0,X1)
#define XMFMA(Q, X0, X1) do {                                                  \
    uint4 xf_;                                                                 \
    xf_.x = pk2bf(bcf((X0).x), bcf((X0).y)); xf_.y = pk2bf(bcf((X0).z), bcf((X0).w)); \
    xf_.z = pk2bf(bcf((X1).x), bcf((X1).y)); xf_.w = pk2bf(bcf((X1).z), bcf((X1).w)); \
    _Pragma("unroll")                                                          \
    for (int g_ = 0; g_ < 4; ++g_)                                             \
        acc[g_] = __builtin_amdgcn_mfma_f32_16x16x32_bf16(                     \
            __builtin_bit_cast(bf16x8, xf_), __builtin_bit_cast(bf16x8, bwx[g_][Q]), \
            acc[g_], 0, 0, 0);                                                 \
} while (0)

__global__ void __launch_bounds__(64, 1)
lstm_kernel(const float* __restrict__ x,
            const float* __restrict__ f_wh, const float* __restrict__ f_wx, const float* __restrict__ f_b,
            const float* __restrict__ p_wh, const float* __restrict__ p_wx, const float* __restrict__ p_b,
            const float* __restrict__ c_wh, const float* __restrict__ c_wx, const float* __restrict__ c_b,
            const float* __restrict__ o_wh, const float* __restrict__ o_wx, const float* __restrict__ o_b,
            float* __restrict__ out, uint8_t* __restrict__ ws)
{
    const int lane = (int)threadIdx.x;    // 0..63
    const int fr   = lane & 15;           // A-row / B-col / D-col index
    const int fkc  = lane >> 4;           // K-chunk / D-row-group index
    const int blk  = (int)blockIdx.x;
    const int grp  = blk & 15;            // row-group (16 batch rows)
    const int cwg  = blk >> 4;            // column slice (16 H cols)
    const int grow0 = grp << 4;
    const int hc0   = cwg << 4;

    uint8_t* sbase = ws + 4096;

    // ---- weights -> VGPRs: B-frag mapping col = fr, k = q*32 + fkc*8 + i ----
    const float* whp[4] = { f_wh, p_wh, c_wh, o_wh };
    const float* wxp[4] = { f_wx, p_wx, c_wx, o_wx };
    const float* bpp[4] = { f_b,  p_b,  c_b,  o_b  };
    uint4 bwh[4][8], bwx[4][4];
    float bias4[4];
    #pragma unroll
    for (int g = 0; g < 4; ++g) {
        const float* W = whp[g];
        #pragma unroll
        for (int q = 0; q < 8; ++q) {
            const int k0 = q * 32 + fkc * 8;
            float v[8];
            #pragma unroll
            for (int i = 0; i < 8; ++i) v[i] = W[(size_t)(k0 + i) * H_DIM + hc0 + fr];
            bwh[g][q].x = pk2bf(v[0], v[1]); bwh[g][q].y = pk2bf(v[2], v[3]);
            bwh[g][q].z = pk2bf(v[4], v[5]); bwh[g][q].w = pk2bf(v[6], v[7]);
        }
        const float* Wx = wxp[g];
        #pragma unroll
        for (int q = 0; q < 4; ++q) {
            const int k0 = q * 32 + fkc * 8;
            float v[8];
            #pragma unroll
            for (int i = 0; i < 8; ++i) v[i] = Wx[(size_t)(k0 + i) * H_DIM + hc0 + fr];
            bwx[g][q].x = pk2bf(v[0], v[1]); bwx[g][q].y = pk2bf(v[2], v[3]);
            bwx[g][q].z = pk2bf(v[4], v[5]); bwx[g][q].w = pk2bf(v[6], v[7]);
        }
        bias4[g] = bpp[g][hc0 + fr];
    }

    // exchange bases: gather row grow0+fr, byte base += fkc*32 (colpairs q*16+fkc*4+{0..3})
    const uint8_t* spA = sbase +          (size_t)(grow0 + fr) * 1024 + (size_t)fkc * 32;
    const uint8_t* spB = sbase + 262144 + (size_t)(grow0 + fr) * 1024 + (size_t)fkc * 32;
    // publish: rows grow0 + fkc*4 + j (j*1024 offsets), colpair cwg*8 + fr/2
    uint8_t* pbA = sbase +          (size_t)(grow0 + fkc * 4) * 1024 + (size_t)(cwg * 8 + (fr >> 1)) * 8;
    uint8_t* pbB = sbase + 262144 + (size_t)(grow0 + fkc * 4) * 1024 + (size_t)(cwg * 8 + (fr >> 1)) * 8;
    // x: row grow0+fr, float offset fkc*8; +512B per step
    const uint8_t* xcur = (const uint8_t*)(x + (size_t)(grow0 + fr) * (T_STEPS * I_DIM) + fkc * 8);

    // pre-loop publish: s0 = 0, tag 1, parity 0 (fire-and-forget; stores have no outputs)
    if ((lane & 1) == 0) {
        u32x2 pd; pd.x = 0u; pd.y = 1u;
        asm volatile(
            "global_store_dwordx2 %[pb], %[pd], off sc0 sc1\n\t"
            "global_store_dwordx2 %[pb], %[pd], off offset:1024 sc0 sc1\n\t"
            "global_store_dwordx2 %[pb], %[pd], off offset:2048 sc0 sc1\n\t"
            "global_store_dwordx2 %[pb], %[pd], off offset:3072 sc0 sc1"
            :: [pb]"v"(pbA), [pd]"v"(pd) : "memory");
    }

    uint4 sg0, sg1, sg2, sg3, sg4, sg5, sg6, sg7;
    uint4 sg8, sg9, sg10, sg11, sg12, sg13, sg14, sg15;
    uint4 xr0, xr1, xr2, xr3, xr4, xr5, xr6, xr7;

    float l_reg[4] = {0.f, 0.f, 0.f, 0.f};
    float s_fin[4] = {0.f, 0.f, 0.f, 0.f};
    float l_fin[4] = {0.f, 0.f, 0.f, 0.f};

    for (int t = 0; t < T_STEPS; ++t) {
        const uint32_t e = (uint32_t)t + 1u;
        const uint8_t* sp = (t & 1) ? spB : spA;

        // ---- ONE asm block: issue 16-slot gather + 8 x-loads, wait ALL inside ----
        // (outputs valid at exit -> spill-safe; x HBM latency overlaps gather RT)
        asm volatile(
            "global_load_dwordx4 %[g0], %[sp], off sc0 sc1\n\t"
            "global_load_dwordx4 %[g1], %[sp], off offset:16 sc0 sc1\n\t"
            "global_load_dwordx4 %[g2], %[sp], off offset:128 sc0 sc1\n\t"
            "global_load_dwordx4 %[g3], %[sp], off offset:144 sc0 sc1\n\t"
            "global_load_dwordx4 %[g4], %[sp], off offset:256 sc0 sc1\n\t"
            "global_load_dwordx4 %[g5], %[sp], off offset:272 sc0 sc1\n\t"
            "global_load_dwordx4 %[g6], %[sp], off offset:384 sc0 sc1\n\t"
            "global_load_dwordx4 %[g7], %[sp], off offset:400 sc0 sc1\n\t"
            "global_load_dwordx4 %[g8], %[sp], off offset:512 sc0 sc1\n\t"
            "global_load_dwordx4 %[g9], %[sp], off offset:528 sc0 sc1\n\t"
            "global_load_dwordx4 %[g10], %[sp], off offset:640 sc0 sc1\n\t"
            "global_load_dwordx4 %[g11], %[sp], off offset:656 sc0 sc1\n\t"
            "global_load_dwordx4 %[g12], %[sp], off offset:768 sc0 sc1\n\t"
            "global_load_dwordx4 %[g13], %[sp], off offset:784 sc0 sc1\n\t"
            "global_load_dwordx4 %[g14], %[sp], off offset:896 sc0 sc1\n\t"
            "global_load_dwordx4 %[g15], %[sp], off offset:912 sc0 sc1\n\t"
            "global_load_dwordx4 %[x0], %[xp], off\n\t"
            "global_load_dwordx4 %[x1], %[xp], off offset:16\n\t"
            "global_load_dwordx4 %[x2], %[xp], off offset:128\n\t"
            "global_load_dwordx4 %[x3], %[xp], off offset:144\n\t"
            "global_load_dwordx4 %[x4], %[xp], off offset:256\n\t"
            "global_load_dwordx4 %[x5], %[xp], off offset:272\n\t"
            "global_load_dwordx4 %[x6], %[xp], off offset:384\n\t"
            "global_load_dwordx4 %[x7], %[xp], off offset:400\n\t"
            "s_waitcnt vmcnt(0)"
            : [g0]"=&v"(sg0), [g1]"=&v"(sg1), [g2]"=&v"(sg2), [g3]"=&v"(sg3),
              [g4]"=&v"(sg4), [g5]"=&v"(sg5), [g6]"=&v"(sg6), [g7]"=&v"(sg7),
              [g8]"=&v"(sg8), [g9]"=&v"(sg9), [g10]"=&v"(sg10), [g11]"=&v"(sg11),
              [g12]"=&v"(sg12), [g13]"=&v"(sg13), [g14]"=&v"(sg14), [g15]"=&v"(sg15),
              [x0]"=&v"(xr0), [x1]"=&v"(xr1), [x2]"=&v"(xr2), [x3]"=&v"(xr3),
              [x4]"=&v"(xr4), [x5]"=&v"(xr5), [x6]"=&v"(xr6), [x7]"=&v"(xr7)
            : [sp]"v"(sp), [xp]"v"(xcur)
            : "memory");

        // poll: retry block also waits internally -> outputs valid at exit
        uint32_t m = TAGOR(e);
        while (__any(m != 0)) {
            asm volatile(
                "global_load_dwordx4 %[g0], %[sp], off sc0 sc1\n\t"
                "global_load_dwordx4 %[g1], %[sp], off offset:16 sc0 sc1\n\t"
                "global_load_dwordx4 %[g2], %[sp], off offset:128 sc0 sc1\n\t"
                "global_load_dwordx4 %[g3], %[sp], off offset:144 sc0 sc1\n\t"
                "global_load_dwordx4 %[g4], %[sp], off offset:256 sc0 sc1\n\t"
                "global_load_dwordx4 %[g5], %[sp], off offset:272 sc0 sc1\n\t"
                "global_load_dwordx4 %[g6], %[sp], off offset:384 sc0 sc1\n\t"
                "global_load_dwordx4 %[g7], %[sp], off offset:400 sc0 sc1\n\t"
                "global_load_dwordx4 %[g8], %[sp], off offset:512 sc0 sc1\n\t"
                "global_load_dwordx4 %[g9], %[sp], off offset:528 sc0 sc1\n\t"
                "global_load_dwordx4 %[g10], %[sp], off offset:640 sc0 sc1\n\t"
                "global_load_dwordx4 %[g11], %[sp], off offset:656 sc0 sc1\n\t"
                "global_load_dwordx4 %[g12], %[sp], off offset:768 sc0 sc1\n\t"
                "global_load_dwordx4 %[g13], %[sp], off offset:784 sc0 sc1\n\t"
                "global_load_dwordx4 %[g14], %[sp], off offset:896 sc0 sc1\n\t"
                "global_load_dwordx4 %[g15], %[sp], off offset:912 sc0 sc1\n\t"
                "s_waitcnt vmcnt(0)"
                : [g0]"=&v"(sg0), [g1]"=&v"(sg1), [g2]"=&v"(sg2), [g3]"=&v"(sg3),
                  [g4]"=&v"(sg4), [g5]"=&v"(sg5), [g6]"=&v"(sg6), [g7]"=&v"(sg7),
                  [g8]"=&v"(sg8), [g9]"=&v"(sg9), [g10]"=&v"(sg10), [g11]"=&v"(sg11),
                  [g12]"=&v"(sg12), [g13]"=&v"(sg13), [g14]"=&v"(sg14), [g15]"=&v"(sg15)
                : [sp]"v"(sp)
                : "memory");
            m = TAGOR(e);
        }

        // MFMAs: 4 gates, 4 x-chunks + 8 s-chunks, 4 independent acc chains
        f32x4 acc[4];
        #pragma unroll
        for (int g = 0; g < 4; ++g) acc[g] = (f32x4){0.f, 0.f, 0.f, 0.f};
        XMFMA(0, xr0, xr1); XMFMA(1, xr2, xr3); XMFMA(2, xr4, xr5); XMFMA(3, xr6, xr7);
        SMFMA(0, sg0, sg1);  SMFMA(1, sg2, sg3);  SMFMA(2, sg4, sg5);  SMFMA(3, sg6, sg7);
        SMFMA(4, sg8, sg9);  SMFMA(5, sg10, sg11); SMFMA(6, sg12, sg13); SMFMA(7, sg14, sg15);

        // activation + combine, lane-local (D: row = fkc*4+j, col = fr, same map all gates)
        float snew[4];
        #pragma unroll
        for (int j = 0; j < 4; ++j) {
            const float fg  = sigmoid_(acc[0][j] + bias4[0]);
            const float pot = tanh_   (acc[1][j] + bias4[1]);
            const float prc = sigmoid_(acc[2][j] + bias4[2]);
            const float og  = sigmoid_(acc[3][j] + bias4[3]);
            const float lnew = fg * l_reg[j] + prc * pot;
            snew[j] = tanh_(lnew) * og;
            l_reg[j] = lnew;
        }
        if (t == T_STEPS - 1) {
            #pragma unroll
            for (int j = 0; j < 4; ++j) { s_fin[j] = snew[j]; l_fin[j] = l_reg[j]; }
            break;
        }

        // pack: even lane holds even col; odd col from lane^1
        uint32_t sb0 = f2bf(snew[0]), sb1 = f2bf(snew[1]);
        uint32_t sb2 = f2bf(snew[2]), sb3 = f2bf(snew[3]);
        uint32_t ob0 = (uint32_t)__shfl_xor((int)sb0, 1, 64);
        uint32_t ob1 = (uint32_t)__shfl_xor((int)sb1, 1, 64);
        uint32_t ob2 = (uint32_t)__shfl_xor((int)sb2, 1, 64);
        uint32_t ob3 = (uint32_t)__shfl_xor((int)sb3, 1, 64);

        // publish s(t+1): tagged slots, fire-and-forget (acks drain inside next big block)
        {
            uint8_t* pb = ((t + 1) & 1) ? pbB : pbA;
            const uint32_t tg = (uint32_t)t + 2u;
            if ((lane & 1) == 0) {
                u32x2 p0; p0.x = (sb0 & 0xFFFFu) | (ob0 << 16); p0.y = tg;
                u32x2 p1; p1.x = (sb1 & 0xFFFFu) | (ob1 << 16); p1.y = tg;
                u32x2 p2; p2.x = (sb2 & 0xFFFFu) | (ob2 << 16); p2.y = tg;
                u32x2 p3; p3.x = (sb3 & 0xFFFFu) | (ob3 << 16); p3.y = tg;
                asm volatile(
                    "global_store_dwordx2 %[pb], %[p0], off sc0 sc1\n\t"
                    "global_store_dwordx2 %[pb], %[p1], off offset:1024 sc0 sc1\n\t"
                    "global_store_dwordx2 %[pb], %[p2], off offset:2048 sc0 sc1\n\t"
                    "global_store_dwordx2 %[pb], %[p3], off offset:3072 sc0 sc1"
                    :: [pb]"v"(pb), [p0]"v"(p0), [p1]"v"(p1), [p2]"v"(p2), [p3]"v"(p3)
                    : "memory");
            }
        }
        xcur += 512;
    }

    // outputs: short_term then long_term, [256][256] f32; lane writes rows fkc*4+j, col fr
    #pragma unroll
    for (int j = 0; j < 4; ++j) {
        const size_t row = (size_t)(grow0 + fkc * 4 + j);
        out[row * H_DIM + hc0 + fr] = s_fin[j];
        out[(size_t)H_DIM * H_DIM + row * H_DIM + hc0 + fr] = l_fin[j];
    }
}

extern "C" void kernel_launch(void* const* d_in, const int* in_sizes, int n_in,
                              void* d_out, int out_size, void* d_ws, size_t ws_size,
                              hipStream_t stream) {
    const float* x    = (const float*)d_in[0];
    const float* f_wh = (const float*)d_in[1];
    const float* f_wx = (const float*)d_in[2];
    const float* f_b  = (const float*)d_in[3];
    const float* p_wh = (const float*)d_in[4];
    const float* p_wx = (const float*)d_in[5];
    const float* p_b  = (const float*)d_in[6];
    const float* c_wh = (const float*)d_in[7];
    const float* c_wx = (const float*)d_in[8];
    const float* c_b  = (const float*)d_in[9];
    const float* o_wh = (const float*)d_in[10];
    const float* o_wx = (const float*)d_in[11];
    const float* o_b  = (const float*)d_in[12];
    float* outp = (float*)d_out;
    uint8_t* wsp = (uint8_t*)d_ws;

    // tags must be zero every call (graph replays leave stale tags)
    hipMemsetAsync(d_ws, 0, 4096 + 2 * 262144, stream);

    // PLAIN launch: 256 one-wave blocks are co-resident by capacity.
    lstm_kernel<<<dim3(256), dim3(64), 0, stream>>>(
        x, f_wh, f_wx, f_b, p_wh, p_wx, p_b, c_wh, c_wx, c_b, o_wh, o_wx, o_b, outp, wsp);
}